// Round 1
// baseline (17239.828 us; speedup 1.0000x reference)
//
#include <hip/hip_runtime.h>
#include <math.h>

#define NN 1024     // nodes
#define BB 64       // batch
#define DD 10       // embedding dim
#define TT 12       // timesteps

// ---------------------------------------------------------------------------
// A = softmax(relu(E @ E^T), axis=1)   one block per row n
// ---------------------------------------------------------------------------
__global__ __launch_bounds__(256) void build_A(const float* __restrict__ E,
                                               float* __restrict__ A) {
  __shared__ float row[NN];
  __shared__ float red[256];
  int n = blockIdx.x;
  float e[DD];
#pragma unroll
  for (int d = 0; d < DD; d++) e[d] = E[n * DD + d];
  float mx = -1e30f;
  for (int m = threadIdx.x; m < NN; m += 256) {
    float s = 0.f;
#pragma unroll
    for (int d = 0; d < DD; d++) s += e[d] * E[m * DD + d];
    s = fmaxf(s, 0.f);
    row[m] = s;
    mx = fmaxf(mx, s);
  }
  red[threadIdx.x] = mx;
  __syncthreads();
  for (int w = 128; w > 0; w >>= 1) {
    if (threadIdx.x < w) red[threadIdx.x] = fmaxf(red[threadIdx.x], red[threadIdx.x + w]);
    __syncthreads();
  }
  mx = red[0];
  __syncthreads();
  float sum = 0.f;
  for (int m = threadIdx.x; m < NN; m += 256) {
    float v = expf(row[m] - mx);
    row[m] = v;
    sum += v;
  }
  red[threadIdx.x] = sum;
  __syncthreads();
  for (int w = 128; w > 0; w >>= 1) {
    if (threadIdx.x < w) red[threadIdx.x] += red[threadIdx.x + w];
    __syncthreads();
  }
  float inv = 1.f / red[0];
  for (int m = threadIdx.x; m < NN; m += 256) A[n * NN + m] = row[m] * inv;
}

// ---------------------------------------------------------------------------
// Y[1024, F] = A[1024, 1024] @ X[1024, F]     (F % 64 == 0)
// 64x64 tile, 16 K-slice, 4x4 per thread, fp32
// ---------------------------------------------------------------------------
__global__ __launch_bounds__(256) void gemm_nn(const float* __restrict__ A,
                                               const float* __restrict__ X,
                                               float* __restrict__ Y, int F) {
  __shared__ float As[16][68];  // [k][m]
  __shared__ float Xs[16][68];  // [k][f]
  int tx = threadIdx.x & 15, ty = threadIdx.x >> 4;
  int f0 = blockIdx.x * 64, m0 = blockIdx.y * 64;
  float acc[4][4] = {{0.f}};
  for (int k0 = 0; k0 < NN; k0 += 16) {
#pragma unroll
    for (int r = 0; r < 4; r++) {
      int m = (threadIdx.x >> 4) + r * 16;
      int k = threadIdx.x & 15;
      As[k][m] = A[(size_t)(m0 + m) * NN + (k0 + k)];
    }
#pragma unroll
    for (int r = 0; r < 4; r++) {
      int f = threadIdx.x & 63;
      int k = (threadIdx.x >> 6) + r * 4;
      Xs[k][f] = X[(size_t)(k0 + k) * F + (f0 + f)];
    }
    __syncthreads();
#pragma unroll
    for (int kk = 0; kk < 16; kk++) {
      float a[4], b[4];
#pragma unroll
      for (int i = 0; i < 4; i++) a[i] = As[kk][ty * 4 + i];
#pragma unroll
      for (int j = 0; j < 4; j++) b[j] = Xs[kk][tx * 4 + j];
#pragma unroll
      for (int i = 0; i < 4; i++)
#pragma unroll
        for (int j = 0; j < 4; j++) acc[i][j] += a[i] * b[j];
    }
    __syncthreads();
  }
#pragma unroll
  for (int i = 0; i < 4; i++)
#pragma unroll
    for (int j = 0; j < 4; j++)
      Y[(size_t)(m0 + ty * 4 + i) * F + f0 + tx * 4 + j] = acc[i][j];
}

// ---------------------------------------------------------------------------
// Per-node adaptive GEMM:
//   Y[n,b,co0+o] = act( sum_{k,i} xg[n,b,k,i] * (sum_d E[n,d] Wp[d,k,i,o']) + bias )
// xg k=0 -> Cbuf[n,b,i], k=1 -> Gbuf[n,b,i].  One block per (node, 64-col chunk).
// ---------------------------------------------------------------------------
template <int CIN, int COT>
__global__ __launch_bounds__(256) void node_gemm(
    const float* __restrict__ Cbuf, const float* __restrict__ Gbuf,
    const float* __restrict__ E, const float* __restrict__ Wp,
    const float* __restrict__ bp, float* __restrict__ Y, int act) {
  constexpr int K2 = 2 * CIN;
  constexpr int K2R = (K2 + 15) & ~15;
  __shared__ float Wn[K2R][64];
  __shared__ float Xs[16][68];
  int n = blockIdx.x;
  int co0 = blockIdx.y * 64;
  float e[DD];
#pragma unroll
  for (int d = 0; d < DD; d++) e[d] = E[n * DD + d];
  // build node-adaptive weight tile in LDS
  for (int idx = threadIdx.x; idx < K2R * 64; idx += 256) {
    int i2 = idx >> 6, o = idx & 63;
    float s = 0.f;
    if (i2 < K2) {
      int kk = (i2 >= CIN) ? 1 : 0;
      int ii = i2 - kk * CIN;
      const float* wp = Wp + (size_t)(kk * CIN + ii) * COT + co0 + o;
#pragma unroll
      for (int d = 0; d < DD; d++) s += e[d] * wp[(size_t)d * 2 * CIN * COT];
    }
    Wn[i2][o] = s;
  }
  __syncthreads();
  int tx = threadIdx.x & 15, ty = threadIdx.x >> 4;
  float acc[4][4] = {{0.f}};
  for (int k0 = 0; k0 < K2R; k0 += 16) {
#pragma unroll
    for (int r = 0; r < 4; r++) {
      int idx = threadIdx.x + r * 256;
      int b = idx >> 4, kq = idx & 15;
      int i2 = k0 + kq;
      float v = 0.f;
      if (i2 < CIN)       v = Cbuf[(size_t)(n * 64 + b) * CIN + i2];
      else if (i2 < K2)   v = Gbuf[(size_t)(n * 64 + b) * CIN + (i2 - CIN)];
      Xs[kq][b] = v;
    }
    __syncthreads();
#pragma unroll
    for (int kq = 0; kq < 16; kq++) {
      float a[4], w[4];
#pragma unroll
      for (int i = 0; i < 4; i++) a[i] = Xs[kq][ty * 4 + i];
#pragma unroll
      for (int j = 0; j < 4; j++) w[j] = Wn[k0 + kq][tx * 4 + j];
#pragma unroll
      for (int i = 0; i < 4; i++)
#pragma unroll
        for (int j = 0; j < 4; j++) acc[i][j] += a[i] * w[j];
    }
    __syncthreads();
  }
  float bias[4];
#pragma unroll
  for (int j = 0; j < 4; j++) {
    int o = co0 + tx * 4 + j;
    float s = 0.f;
#pragma unroll
    for (int d = 0; d < DD; d++) s += e[d] * bp[d * COT + o];
    bias[j] = s;
  }
#pragma unroll
  for (int i = 0; i < 4; i++) {
    int b = ty * 4 + i;
#pragma unroll
    for (int j = 0; j < 4; j++) {
      float v = acc[i][j] + bias[j];
      v = act ? tanhf(v) : 1.f / (1.f + expf(-v));
      Y[(size_t)(n * 64 + b) * COT + co0 + tx * 4 + j] = v;
    }
  }
}

// ---------------------------------------------------------------------------
// elementwise helpers.  h layout: [n, b, c] (c fastest).
// ---------------------------------------------------------------------------
__global__ void init_h(const float* __restrict__ init, float* __restrict__ h0,
                       float* __restrict__ h1) {
  int idx = blockIdx.x * 256 + threadIdx.x;  // over N*B*64
  int c = idx & 63, b = (idx >> 6) & 63, n = idx >> 12;
  h0[idx] = init[((size_t)(0 * BB + b) * NN + n) * 64 + c];
  h1[idx] = init[((size_t)(1 * BB + b) * NN + n) * 64 + c];
}

__global__ void transpose_xt(const float* __restrict__ x, float* __restrict__ xt, int t) {
  int idx = blockIdx.x * 256 + threadIdx.x;  // over N*B*2
  int i = idx & 1, b = (idx >> 1) & 63, n = idx >> 7;
  xt[idx] = x[(((size_t)b * TT + t) * NN + n) * 2 + i];
}

__global__ void concat_x_l0(const float* __restrict__ xt, float* __restrict__ C) {
  int idx = blockIdx.x * 256 + threadIdx.x;  // N*B*2
  int i = idx & 1, nb = idx >> 1;
  C[(size_t)nb * 66 + i] = xt[idx];
}

__global__ void concat_h_l0(const float* __restrict__ h, const float* __restrict__ zr,
                            float* __restrict__ C, int use_z) {
  int idx = blockIdx.x * 256 + threadIdx.x;  // N*B*64
  int j = idx & 63, nb = idx >> 6;
  float v = h[idx];
  if (use_z) v *= zr[(size_t)nb * 128 + j];
  C[(size_t)nb * 66 + 2 + j] = v;
}

__global__ void concat_x_l1(const float* __restrict__ x1, float* __restrict__ C) {
  int idx = blockIdx.x * 256 + threadIdx.x;  // N*B*64
  int j = idx & 63, nb = idx >> 6;
  C[(size_t)nb * 128 + j] = x1[idx];
}

__global__ void concat_h_l1(const float* __restrict__ h, const float* __restrict__ zr,
                            float* __restrict__ C, int use_z) {
  int idx = blockIdx.x * 256 + threadIdx.x;  // N*B*64
  int j = idx & 63, nb = idx >> 6;
  float v = h[idx];
  if (use_z) v *= zr[(size_t)nb * 128 + j];
  C[(size_t)nb * 128 + 64 + j] = v;
}

__global__ void h_update(float* __restrict__ h, const float* __restrict__ zr,
                         const float* __restrict__ hc) {
  int idx = blockIdx.x * 256 + threadIdx.x;  // N*B*64
  int j = idx & 63, nb = idx >> 6;
  float r = zr[(size_t)nb * 128 + 64 + j];
  h[idx] = r * h[idx] + (1.f - r) * hc[idx];
}

__global__ void final_l0(const float* __restrict__ h0, const float* __restrict__ st2,
                         const float* __restrict__ Wl, const float* __restrict__ bl,
                         const float* __restrict__ ratio, float* __restrict__ x1) {
  int idx = blockIdx.x * 256 + threadIdx.x;  // N*B*64
  int o = idx & 63, nb = idx >> 6;
  float k = 0.5f + 0.5f * ratio[0];
  float s = st2[(size_t)nb * 2 + 0] * Wl[o] + st2[(size_t)nb * 2 + 1] * Wl[64 + o] + bl[o];
  x1[idx] = k * h0[idx] + (1.f - k) * s;
}

__global__ void final_l1(const float* __restrict__ h1, const float* __restrict__ st,
                         const float* __restrict__ ratio, float* __restrict__ out, int t) {
  int idx = blockIdx.x * 256 + threadIdx.x;  // N*B*64
  int o = idx & 63, b = (idx >> 6) & 63, n = idx >> 12;
  float k = 0.5f + 0.5f * ratio[0];
  float v = k * h1[idx] + (1.f - k) * st[idx];
  out[(((size_t)b * TT + t) * NN + n) * 64 + o] = v;
}

__global__ void write_hidden(const float* __restrict__ h0, const float* __restrict__ h1,
                             float* __restrict__ out_hid) {
  int idx = blockIdx.x * 256 + threadIdx.x;  // over 2*B*N*64
  int c = idx & 63, n = (idx >> 6) & 1023, b = (idx >> 16) & 63, l = idx >> 22;
  const float* h = l ? h1 : h0;
  out_hid[idx] = h[((size_t)(n * 64 + b)) * 64 + c];
}

// ---------------------------------------------------------------------------
extern "C" void kernel_launch(void* const* d_in, const int* in_sizes, int n_in,
                              void* d_out, int out_size, void* d_ws, size_t ws_size,
                              hipStream_t stream) {
  const float* x     = (const float*)d_in[0];
  const float* inis  = (const float*)d_in[1];
  const float* E     = (const float*)d_in[2];
  const float* adj   = (const float*)d_in[3];
  const float* ratio = (const float*)d_in[4];
  const float* Wg0   = (const float*)d_in[5];
  const float* bg0   = (const float*)d_in[6];
  const float* Wu0   = (const float*)d_in[7];
  const float* bu0   = (const float*)d_in[8];
  const float* Wg1   = (const float*)d_in[9];
  const float* bg1   = (const float*)d_in[10];
  const float* Wu1   = (const float*)d_in[11];
  const float* bu1   = (const float*)d_in[12];
  const float* Wl    = (const float*)d_in[13];
  const float* bl    = (const float*)d_in[14];
  float* out = (float*)d_out;

  float* ws = (float*)d_ws;
  float* Abuf = ws;                       // 1M
  float* h0   = ws + 1048576;             // 4M
  float* h1   = ws + 5242880;             // 4M
  float* x1   = ws + 9437184;             // 4M
  float* Cb   = ws + 13631488;            // 8M
  float* Gb   = ws + 22020096;            // 8M
  float* zr   = ws + 30408704;            // 8M
  float* stb  = ws + 38797312;            // 4M (shared: hc then static)
  float* hc   = stb;
  float* xt   = ws + 42991616;            // 128K

  const int EW = 16384;  // N*B*64 / 256
  build_A<<<NN, 256, 0, stream>>>(E, Abuf);
  init_h<<<EW, 256, 0, stream>>>(inis, h0, h1);

  for (int t = 0; t < TT; t++) {
    // ---- layer 0 (Cin = 2+64 = 66) ----
    transpose_xt<<<512, 256, 0, stream>>>(x, xt, t);
    concat_x_l0<<<512, 256, 0, stream>>>(xt, Cb);
    concat_h_l0<<<EW, 256, 0, stream>>>(h0, zr, Cb, 0);
    gemm_nn<<<dim3(66, 16), 256, 0, stream>>>(Abuf, Cb, Gb, 64 * 66);
    node_gemm<66, 128><<<dim3(NN, 2), 256, 0, stream>>>(Cb, Gb, E, Wg0, bg0, zr, 0);
    concat_h_l0<<<EW, 256, 0, stream>>>(h0, zr, Cb, 1);
    gemm_nn<<<dim3(66, 16), 256, 0, stream>>>(Abuf, Cb, Gb, 64 * 66);
    node_gemm<66, 64><<<dim3(NN, 1), 256, 0, stream>>>(Cb, Gb, E, Wu0, bu0, hc, 1);
    h_update<<<EW, 256, 0, stream>>>(h0, zr, hc);
    gemm_nn<<<dim3(2, 16), 256, 0, stream>>>(adj, xt, stb, 128);
    final_l0<<<EW, 256, 0, stream>>>(h0, stb, Wl, bl, ratio, x1);
    // ---- layer 1 (Cin = 64+64 = 128) ----
    concat_x_l1<<<EW, 256, 0, stream>>>(x1, Cb);
    concat_h_l1<<<EW, 256, 0, stream>>>(h1, zr, Cb, 0);
    gemm_nn<<<dim3(128, 16), 256, 0, stream>>>(Abuf, Cb, Gb, 64 * 128);
    node_gemm<128, 128><<<dim3(NN, 2), 256, 0, stream>>>(Cb, Gb, E, Wg1, bg1, zr, 0);
    concat_h_l1<<<EW, 256, 0, stream>>>(h1, zr, Cb, 1);
    gemm_nn<<<dim3(128, 16), 256, 0, stream>>>(Abuf, Cb, Gb, 64 * 128);
    node_gemm<128, 64><<<dim3(NN, 1), 256, 0, stream>>>(Cb, Gb, E, Wu1, bu1, hc, 1);
    h_update<<<EW, 256, 0, stream>>>(h1, zr, hc);
    gemm_nn<<<dim3(64, 16), 256, 0, stream>>>(adj, x1, stb, 64 * 64);
    final_l1<<<EW, 256, 0, stream>>>(h1, stb, ratio, out, t);
  }
  write_hidden<<<32768, 256, 0, stream>>>(h0, h1, out + (size_t)BB * TT * NN * 64);
}

// Round 2
// 14501.956 us; speedup vs baseline: 1.1888x; 1.1888x over previous
//
#include <hip/hip_runtime.h>
#include <math.h>

#define NN 1024     // nodes
#define BB 64       // batch
#define DD 10       // embedding dim
#define TT 12       // timesteps

// ---------------------------------------------------------------------------
// A = softmax(relu(E @ E^T), axis=1)   one block per row n
// ---------------------------------------------------------------------------
__global__ __launch_bounds__(256) void build_A(const float* __restrict__ E,
                                               float* __restrict__ A) {
  __shared__ float row[NN];
  __shared__ float red[256];
  int n = blockIdx.x;
  float e[DD];
#pragma unroll
  for (int d = 0; d < DD; d++) e[d] = E[n * DD + d];
  float mx = -1e30f;
  for (int m = threadIdx.x; m < NN; m += 256) {
    float s = 0.f;
#pragma unroll
    for (int d = 0; d < DD; d++) s += e[d] * E[m * DD + d];
    s = fmaxf(s, 0.f);
    row[m] = s;
    mx = fmaxf(mx, s);
  }
  red[threadIdx.x] = mx;
  __syncthreads();
  for (int w = 128; w > 0; w >>= 1) {
    if (threadIdx.x < w) red[threadIdx.x] = fmaxf(red[threadIdx.x], red[threadIdx.x + w]);
    __syncthreads();
  }
  mx = red[0];
  __syncthreads();
  float sum = 0.f;
  for (int m = threadIdx.x; m < NN; m += 256) {
    float v = expf(row[m] - mx);
    row[m] = v;
    sum += v;
  }
  red[threadIdx.x] = sum;
  __syncthreads();
  for (int w = 128; w > 0; w >>= 1) {
    if (threadIdx.x < w) red[threadIdx.x] += red[threadIdx.x + w];
    __syncthreads();
  }
  float inv = 1.f / red[0];
  for (int m = threadIdx.x; m < NN; m += 256) A[n * NN + m] = row[m] * inv;
}

// ---------------------------------------------------------------------------
// Y[1024,F] = A[1024,1024] @ X[1024,F].  Tile 128x128, BK=16, 8x8/thread,
// LDS double-buffered (one barrier/iter), float4 loads.  Up to 2 fused ops
// selected by blockIdx.z.
// ---------------------------------------------------------------------------
__global__ __launch_bounds__(256) void gemm128(
    const float* __restrict__ A0, const float* __restrict__ X0, float* __restrict__ Y0,
    const float* __restrict__ A1, const float* __restrict__ X1, float* __restrict__ Y1,
    int F) {
  const float* A = blockIdx.z ? A1 : A0;
  const float* X = blockIdx.z ? X1 : X0;
  float*       Y = blockIdx.z ? Y1 : Y0;
  __shared__ float As[2][16][132];
  __shared__ float Xs[2][16][132];
  int tid = threadIdx.x;
  int f0 = blockIdx.x * 128, m0 = blockIdx.y * 128;
  int am = tid >> 2;            // 0..63 (row within half-tile)
  int ak = (tid & 3) << 2;      // 0,4,8,12
  int xc = (tid & 31) << 2;     // col 0..124
  int xk = tid >> 5;            // 0..7
  const float* Abase = A + (size_t)(m0 + am) * NN + ak;
  const float* Xbase = X + (size_t)xk * F + f0 + xc;

  float4 pa0 = *(const float4*)(Abase);
  float4 pa1 = *(const float4*)(Abase + (size_t)64 * NN);
  float4 px0 = *(const float4*)(Xbase);
  float4 px1 = *(const float4*)(Xbase + (size_t)8 * F);
  As[0][ak + 0][am] = pa0.x; As[0][ak + 1][am] = pa0.y;
  As[0][ak + 2][am] = pa0.z; As[0][ak + 3][am] = pa0.w;
  As[0][ak + 0][am + 64] = pa1.x; As[0][ak + 1][am + 64] = pa1.y;
  As[0][ak + 2][am + 64] = pa1.z; As[0][ak + 3][am + 64] = pa1.w;
  *(float4*)&Xs[0][xk][xc] = px0;
  *(float4*)&Xs[0][xk + 8][xc] = px1;
  __syncthreads();

  int tx = tid & 15, ty = tid >> 4;
  float acc[8][8] = {};
  int buf = 0;
  for (int k0 = 16; k0 <= NN; k0 += 16) {
    bool more = (k0 < NN);
    if (more) {
      pa0 = *(const float4*)(Abase + k0);
      pa1 = *(const float4*)(Abase + (size_t)64 * NN + k0);
      px0 = *(const float4*)(Xbase + (size_t)k0 * F);
      px1 = *(const float4*)(Xbase + (size_t)(k0 + 8) * F);
    }
#pragma unroll
    for (int kk = 0; kk < 16; kk++) {
      float4 a0 = *(const float4*)&As[buf][kk][ty * 4];
      float4 a1 = *(const float4*)&As[buf][kk][64 + ty * 4];
      float4 b0 = *(const float4*)&Xs[buf][kk][tx * 4];
      float4 b1 = *(const float4*)&Xs[buf][kk][64 + tx * 4];
      float av[8] = {a0.x, a0.y, a0.z, a0.w, a1.x, a1.y, a1.z, a1.w};
      float bv[8] = {b0.x, b0.y, b0.z, b0.w, b1.x, b1.y, b1.z, b1.w};
#pragma unroll
      for (int i = 0; i < 8; i++)
#pragma unroll
        for (int j = 0; j < 8; j++) acc[i][j] += av[i] * bv[j];
    }
    if (more) {
      int nb = buf ^ 1;
      As[nb][ak + 0][am] = pa0.x; As[nb][ak + 1][am] = pa0.y;
      As[nb][ak + 2][am] = pa0.z; As[nb][ak + 3][am] = pa0.w;
      As[nb][ak + 0][am + 64] = pa1.x; As[nb][ak + 1][am + 64] = pa1.y;
      As[nb][ak + 2][am + 64] = pa1.z; As[nb][ak + 3][am + 64] = pa1.w;
      *(float4*)&Xs[nb][xk][xc] = px0;
      *(float4*)&Xs[nb][xk + 8][xc] = px1;
    }
    __syncthreads();
    buf ^= 1;
  }
#pragma unroll
  for (int i = 0; i < 8; i++) {
    int r = m0 + ty * 4 + (i & 3) + (i >> 2) * 64;
    float4 v0 = {acc[i][0], acc[i][1], acc[i][2], acc[i][3]};
    float4 v1 = {acc[i][4], acc[i][5], acc[i][6], acc[i][7]};
    *(float4*)&Y[(size_t)r * F + f0 + tx * 4] = v0;
    *(float4*)&Y[(size_t)r * F + f0 + 64 + tx * 4] = v1;
  }
}

// ---------------------------------------------------------------------------
// Per-node adaptive GEMM over split inputs.
//   K layout: [x(XC) | h(64) | Gx(XC) | Gh(64)],  XC = 2 (layer0) or 64.
//   ZR=1: Co=128, grid(N,2); epilogue sigmoid; y==0 chunk -> outA = z*hmul,
//         y==1 chunk -> outB = r.
//   ZR=0: Co=64, grid(N,1); epilogue tanh -> outB (may alias hp: single
//         block per node, reads precede writes).
// ---------------------------------------------------------------------------
template <int CIN, int COT, int ZR>
__global__ __launch_bounds__(256) void node_gemm(
    const float* __restrict__ xp, const float* __restrict__ hp,
    const float* __restrict__ gxp, const float* __restrict__ ghp,
    const float* __restrict__ E, const float* __restrict__ Wp,
    const float* __restrict__ bp, float* __restrict__ outA,
    float* __restrict__ outB, const float* __restrict__ hmul, int toff) {
  constexpr int XC = (CIN == 66) ? 2 : 64;
  constexpr int K2 = 2 * CIN;
  constexpr int K2R = (K2 + 15) & ~15;
  __shared__ float Wn[K2R][64];
  __shared__ float Xs[16][68];
  int n = blockIdx.x;
  int co0 = blockIdx.y * 64;
  float e[DD];
#pragma unroll
  for (int d = 0; d < DD; d++) e[d] = E[n * DD + d];
  // node-adaptive weight tile (float4 over out cols)
  for (int idx = threadIdx.x; idx < K2R * 16; idx += 256) {
    int i2 = idx >> 4, o4 = (idx & 15) << 2;
    float4 s = {0.f, 0.f, 0.f, 0.f};
    if (i2 < K2) {
      int kk = (i2 >= CIN) ? 1 : 0;
      int ii = i2 - kk * CIN;
      const float* wp = Wp + ((size_t)kk * CIN + ii) * COT + co0 + o4;
#pragma unroll
      for (int d = 0; d < DD; d++) {
        float4 w = *(const float4*)(wp + (size_t)d * 2 * CIN * COT);
        s.x += e[d] * w.x; s.y += e[d] * w.y; s.z += e[d] * w.z; s.w += e[d] * w.w;
      }
    }
    *(float4*)&Wn[i2][o4] = s;
  }
  __syncthreads();

  int tx = threadIdx.x & 15, ty = threadIdx.x >> 4;
  float acc[4][4] = {{0.f}};
  for (int k0 = 0; k0 < K2R; k0 += 16) {
#pragma unroll
    for (int r = 0; r < 4; r++) {
      int idx = threadIdx.x + r * 256;
      int b = idx >> 4, kq = idx & 15;
      int i2 = k0 + kq;
      float v = 0.f;
      if (i2 < XC)
        v = (CIN == 66) ? xp[(size_t)n * 1536 + toff + b * 2 + i2]
                        : xp[((size_t)n * 64 + b) * 64 + i2];
      else if (i2 < CIN)
        v = hp[((size_t)n * 64 + b) * 64 + (i2 - XC)];
      else if (i2 < CIN + XC)
        v = (CIN == 66) ? gxp[(size_t)n * 1536 + toff + b * 2 + (i2 - CIN)]
                        : gxp[((size_t)n * 64 + b) * 64 + (i2 - CIN)];
      else if (i2 < K2)
        v = ghp[((size_t)n * 64 + b) * 64 + (i2 - CIN - XC)];
      Xs[kq][b] = v;
    }
    __syncthreads();
#pragma unroll
    for (int kq = 0; kq < 16; kq++) {
      float a[4], w[4];
#pragma unroll
      for (int i = 0; i < 4; i++) a[i] = Xs[kq][ty * 4 + i];
#pragma unroll
      for (int j = 0; j < 4; j++) w[j] = Wn[k0 + kq][tx * 4 + j];
#pragma unroll
      for (int i = 0; i < 4; i++)
#pragma unroll
        for (int j = 0; j < 4; j++) acc[i][j] += a[i] * w[j];
    }
    __syncthreads();
  }
  float bias[4];
#pragma unroll
  for (int j = 0; j < 4; j++) {
    int o = co0 + tx * 4 + j;
    float s = 0.f;
#pragma unroll
    for (int d = 0; d < DD; d++) s += e[d] * bp[d * COT + o];
    bias[j] = s;
  }
#pragma unroll
  for (int i = 0; i < 4; i++) {
    int b = ty * 4 + i;
#pragma unroll
    for (int j = 0; j < 4; j++) {
      float v = acc[i][j] + bias[j];
      size_t o = ((size_t)n * 64 + b) * 64 + tx * 4 + j;
      if (ZR) {
        v = 1.f / (1.f + expf(-v));
        if (co0 == 0) outA[o] = v * hmul[o];
        else          outB[o] = v;
      } else {
        outB[o] = tanhf(v);
      }
    }
  }
}

// ---------------------------------------------------------------------------
// elementwise.  h layout [n,b,c] (c fastest).
// ---------------------------------------------------------------------------
__global__ void init_h(const float* __restrict__ init, float* __restrict__ h0,
                       float* __restrict__ h1) {
  int idx = blockIdx.x * 256 + threadIdx.x;  // N*B*64
  int c = idx & 63, b = (idx >> 6) & 63, n = idx >> 12;
  h0[idx] = init[((size_t)(0 * BB + b) * NN + n) * 64 + c];
  h1[idx] = init[((size_t)(1 * BB + b) * NN + n) * 64 + c];
}

__global__ void transpose_all(const float* __restrict__ x, float* __restrict__ XT) {
  int idx = blockIdx.x * 256 + threadIdx.x;  // N*T*B*2  -> XT[n][t][b][i]
  int i = idx & 1, b = (idx >> 1) & 63;
  int rest = idx >> 7;         // n*12+t
  int t = rest % 12, n = rest / 12;
  XT[idx] = x[(((size_t)b * TT + t) * NN + n) * 2 + i];
}

__global__ void upd0(float* __restrict__ h0, const float* __restrict__ rbuf,
                     const float* __restrict__ hc, const float* __restrict__ stx,
                     const float* __restrict__ Wl, const float* __restrict__ bl,
                     const float* __restrict__ ratio, float* __restrict__ x1, int toff) {
  int idx = blockIdx.x * 256 + threadIdx.x;  // N*B*64
  int j = idx & 63, nb = idx >> 6, b = nb & 63, n = nb >> 6;
  float k = 0.5f + 0.5f * ratio[0];
  float r = rbuf[idx];
  float hn = r * h0[idx] + (1.f - r) * hc[idx];
  h0[idx] = hn;
  float s0 = stx[(size_t)n * 1536 + toff + b * 2 + 0];
  float s1 = stx[(size_t)n * 1536 + toff + b * 2 + 1];
  float s = s0 * Wl[j] + s1 * Wl[64 + j] + bl[j];
  x1[idx] = k * hn + (1.f - k) * s;
}

__global__ void upd1(float* __restrict__ h1, const float* __restrict__ rbuf,
                     const float* __restrict__ hc, const float* __restrict__ stx1,
                     const float* __restrict__ ratio, float* __restrict__ out, int t) {
  int idx = blockIdx.x * 256 + threadIdx.x;  // N*B*64
  int j = idx & 63, b = (idx >> 6) & 63, n = idx >> 12;
  float k = 0.5f + 0.5f * ratio[0];
  float r = rbuf[idx];
  float hn = r * h1[idx] + (1.f - r) * hc[idx];
  h1[idx] = hn;
  float v = k * hn + (1.f - k) * stx1[idx];
  out[(((size_t)b * TT + t) * NN + n) * 64 + j] = v;
}

__global__ void write_hidden(const float* __restrict__ h0, const float* __restrict__ h1,
                             float* __restrict__ out_hid) {
  int idx = blockIdx.x * 256 + threadIdx.x;  // 2*B*N*64
  int c = idx & 63, n = (idx >> 6) & 1023, b = (idx >> 16) & 63, l = idx >> 22;
  const float* h = l ? h1 : h0;
  out_hid[idx] = h[((size_t)(n * 64 + b)) * 64 + c];
}

// ---------------------------------------------------------------------------
extern "C" void kernel_launch(void* const* d_in, const int* in_sizes, int n_in,
                              void* d_out, int out_size, void* d_ws, size_t ws_size,
                              hipStream_t stream) {
  const float* x     = (const float*)d_in[0];
  const float* inis  = (const float*)d_in[1];
  const float* E     = (const float*)d_in[2];
  const float* adj   = (const float*)d_in[3];
  const float* ratio = (const float*)d_in[4];
  const float* Wg0   = (const float*)d_in[5];
  const float* bg0   = (const float*)d_in[6];
  const float* Wu0   = (const float*)d_in[7];
  const float* bu0   = (const float*)d_in[8];
  const float* Wg1   = (const float*)d_in[9];
  const float* bg1   = (const float*)d_in[10];
  const float* Wu1   = (const float*)d_in[11];
  const float* bu1   = (const float*)d_in[12];
  const float* Wl    = (const float*)d_in[13];
  const float* bl    = (const float*)d_in[14];
  float* out = (float*)d_out;

  float* ws = (float*)d_ws;
  size_t off = 0;
  auto alloc = [&](size_t nel) { float* p = ws + off; off += nel; return p; };
  const size_t HSZ = (size_t)NN * BB * 64;  // 4,194,304
  float* Abuf  = alloc((size_t)NN * NN);    // A matrix
  float* h0    = alloc(HSZ);
  float* h1    = alloc(HSZ);
  float* x1    = alloc(HSZ);
  float* GhX   = alloc(HSZ);                // shared: Gh(t) then Gh1(t)
  float* Gzh   = alloc(HSZ);
  float* Gx1   = alloc(HSZ);
  float* rbuf  = alloc(HSZ);
  float* tmp   = alloc(HSZ);                // z*h, then hc (in place)
  float* XT    = alloc((size_t)NN * TT * BB * 2);
  float* GxAll = alloc((size_t)NN * TT * BB * 2);
  float* stxAll= alloc((size_t)NN * TT * BB * 2);
  // stx1 lives in the out-hidden tail (overwritten by write_hidden at the end)
  float* stx1 = out + (size_t)BB * TT * NN * 64;

  const int EW = 16384;  // N*B*64 / 256
  build_A<<<NN, 256, 0, stream>>>(E, Abuf);
  init_h<<<EW, 256, 0, stream>>>(inis, h0, h1);
  transpose_all<<<6144, 256, 0, stream>>>(x, XT);
  // batched input convs for all t:  GxAll = A@XT, stxAll = adj@XT  (F=1536)
  gemm128<<<dim3(12, 8, 2), 256, 0, stream>>>(Abuf, XT, GxAll, adj, XT, stxAll, 1536);
  // Gh(0) = A @ h0_init
  gemm128<<<dim3(32, 8, 1), 256, 0, stream>>>(Abuf, h0, GhX, nullptr, nullptr, nullptr, 4096);

  for (int t = 0; t < TT; t++) {
    int toff = t * 128;
    // ---- layer 0 ----
    node_gemm<66, 128, 1><<<dim3(NN, 2), 256, 0, stream>>>(
        XT, h0, GxAll, GhX, E, Wg0, bg0, tmp, rbuf, h0, toff);
    gemm128<<<dim3(32, 8, 2), 256, 0, stream>>>(Abuf, tmp, Gzh, Abuf, h1, GhX, 4096);
    node_gemm<66, 64, 0><<<dim3(NN, 1), 256, 0, stream>>>(
        XT, tmp, GxAll, Gzh, E, Wu0, bu0, nullptr, tmp, nullptr, toff);
    upd0<<<EW, 256, 0, stream>>>(h0, rbuf, tmp, stxAll, Wl, bl, ratio, x1, toff);
    // ---- layer 1 ----
    gemm128<<<dim3(32, 8, 2), 256, 0, stream>>>(Abuf, x1, Gx1, adj, x1, stx1, 4096);
    node_gemm<128, 128, 1><<<dim3(NN, 2), 256, 0, stream>>>(
        x1, h1, Gx1, GhX, E, Wg1, bg1, tmp, rbuf, h1, 0);
    if (t < TT - 1) {
      gemm128<<<dim3(32, 8, 2), 256, 0, stream>>>(Abuf, tmp, Gzh, Abuf, h0, GhX, 4096);
    } else {
      gemm128<<<dim3(32, 8, 1), 256, 0, stream>>>(Abuf, tmp, Gzh, nullptr, nullptr, nullptr, 4096);
    }
    node_gemm<128, 64, 0><<<dim3(NN, 1), 256, 0, stream>>>(
        x1, tmp, Gx1, Gzh, E, Wu1, bu1, nullptr, tmp, nullptr, 0);
    upd1<<<EW, 256, 0, stream>>>(h1, rbuf, tmp, stx1, ratio, out, t);
  }
  write_hidden<<<32768, 256, 0, stream>>>(h0, h1, out + (size_t)BB * TT * NN * 64);
}